// Round 4
// baseline (767.121 us; speedup 1.0000x reference)
//
#include <hip/hip_runtime.h>
#include <math.h>

// B=2,H=16,S=2048,D=64 fp32 attention, outputs (O, P). MFMA bf16, barrier-free.
#define NB 2
#define NH 16
#define SL 2048
#define DD 64
#define KC 64
#define NCH (SL / KC)
#define NT 256
#define LPS 68           // slab fp32 row stride (pad +4)

typedef short bf16x8 __attribute__((ext_vector_type(8)));
typedef float f32x4  __attribute__((ext_vector_type(4)));

__device__ __forceinline__ unsigned short f2bf(float x) {
    unsigned u = __float_as_uint(x);
    u += 0x7fffu + ((u >> 16) & 1u);     // round-to-nearest-even
    return (unsigned short)(u >> 16);
}

// ---------------- prep: fp32 -> bf16 elementwise (Q scaled, K raw) -----------
__global__ __launch_bounds__(256)
void cvt_bf16(const float* __restrict__ in, unsigned short* __restrict__ out,
              int n4, float scale)
{
    int i = blockIdx.x * 256 + threadIdx.x;
    if (i >= n4) return;
    float4 v = ((const float4*)in)[i];
    ushort4 o;
    o.x = f2bf(v.x * scale); o.y = f2bf(v.y * scale);
    o.z = f2bf(v.z * scale); o.w = f2bf(v.w * scale);
    ((ushort4*)out)[i] = o;
}

// ---------------- prep: V[bh][s][d] fp32 -> Vt[bh][d][s] bf16 ----------------
__global__ __launch_bounds__(256)
void transpose_v(const float* __restrict__ V, unsigned short* __restrict__ Vt)
{
    __shared__ __align__(16) unsigned short vt[64 * 72];  // [d][r], stride 72
    const int bh = blockIdx.x >> 5;
    const int s0 = (blockIdx.x & 31) * 64;
    const int t  = threadIdx.x;

    const float4* src = (const float4*)(V + ((size_t)bh * SL + s0) * DD);
    #pragma unroll
    for (int i = 0; i < 4; ++i) {
        int idx = t + i * 256;
        int r = idx >> 4, d4 = idx & 15;
        float4 v = src[r * 16 + d4];
        vt[(d4 * 4 + 0) * 72 + r] = f2bf(v.x);
        vt[(d4 * 4 + 1) * 72 + r] = f2bf(v.y);
        vt[(d4 * 4 + 2) * 72 + r] = f2bf(v.z);
        vt[(d4 * 4 + 3) * 72 + r] = f2bf(v.w);
    }
    __syncthreads();
    const int d = t >> 2, seg = t & 3;
    unsigned short* dst = Vt + ((size_t)bh * DD + d) * SL + s0 + seg * 16;
    uint4 p0 = *(const uint4*)&vt[d * 72 + seg * 16];
    uint4 p1 = *(const uint4*)&vt[d * 72 + seg * 16 + 8];
    *(uint4*)dst = p0;
    *(uint4*)(dst + 8) = p1;
}

// ---------------- main fused attention (4 independent waves / block) ---------
__global__ __launch_bounds__(NT, 4)
void attn_mfma(const unsigned short* __restrict__ Qb,
               const unsigned short* __restrict__ Kb,
               const unsigned short* __restrict__ Vt,
               const float* __restrict__ Mg,
               const int* __restrict__ MNg,
               float* __restrict__ Og)
{
    // Per-wave private slab: no cross-wave LDS traffic -> NO barriers anywhere.
    __shared__ __align__(16) float ps[4][16 * LPS];

    const int tid  = threadIdx.x;
    const int w    = tid >> 6;
    const int lane = tid & 63;
    const int l15  = lane & 15;
    const int qd   = lane >> 4;

    // Folded-triangle mapping: block = (pair p, bh). Pair p covers 32-row
    // halves of q-tiles p and 63-p -> EVERY block does ~66 chunk-iters total.
    // Roles rotate by slot k so each SIMD gets a light+heavy role mix.
    const int lin  = blockIdx.x;
    const int xcd  = lin & 7;
    const int iloc = lin >> 3;       // 0..127 within XCD
    const int p    = iloc & 31;      // pair index (also CU slot under RR model)
    const int k    = iloc >> 5;      // 0..3
    const int bh   = xcd * 4 + k;
    const int b    = bh >> 4;
    const int role = (w + k) & 3;    // 0,1: low tile halves; 2,3: high tile
    const int r0   = (role < 2) ? (p * 32 + (role & 1) * 16)
                                : (2016 - p * 32 + (role & 1) * 16);

    const int diag = (MNg[0] != 0) ? -1 : 0;

    // Rows owned by this lane: r0 + qd*4 + reg.  rlim<0 <=> degenerate row.
    int rlim[4]; int anyDeg = 0;
    #pragma unroll
    for (int reg = 0; reg < 4; ++reg) {
        int row = r0 + qd * 4 + reg;
        float m = Mg[(size_t)b * SL + row];
        int rl = row + diag;
        if (m == 0.0f) rl = -1;
        rlim[reg] = rl;
        anyDeg |= (rl < 0);
    }
    const bool waveDeg = __any(anyDeg);
    const int lastB = waveDeg ? (NCH - 1) : ((r0 + 15 + diag) >> 6);

    const unsigned short* Qh  = Qb + (size_t)bh * SL * DD;
    const unsigned short* Kh  = Kb + (size_t)bh * SL * DD;
    const unsigned short* Vth = Vt + (size_t)bh * DD * SL;
    float* Oo   = Og + ((size_t)bh * SL + r0) * DD;
    float* Sout = Og + (size_t)NB * NH * SL * DD
                     + (size_t)bh * SL * SL + (size_t)r0 * SL;
    float* slab = ps[w];

    // Q A-frags (persistent). Q pre-scaled by 0.125*log2(e) at cvt time,
    // so QK^T accumulators are already in exp2 domain: P = exp2(acc).
    const unsigned short* qrow = Qh + (size_t)(r0 + l15) * DD + qd * 8;
    bf16x8 qf0 = *(const bf16x8*)qrow;
    bf16x8 qf1 = *(const bf16x8*)(qrow + 32);

    // ---------------- Phase A: row sums (flattened, 2-ahead K pipeline) ------
    float lacc[4] = {0.0f, 0.0f, 0.0f, 0.0f};
    const int total = (lastB + 1) * 4;      // 16-col tiles; multiple of 4

    auto ldK = [&](int it, bf16x8& f0, bf16x8& f1) {
        const unsigned short* kr = Kh + (size_t)(it * 16 + l15) * DD + qd * 8;
        f0 = *(const bf16x8*)kr;
        f1 = *(const bf16x8*)(kr + 32);
    };
    auto cmpA = [&](int it, bf16x8 f0, bf16x8 f1) {
        f32x4 acc = {0.0f, 0.0f, 0.0f, 0.0f};
        __builtin_amdgcn_s_setprio(1);
        acc = __builtin_amdgcn_mfma_f32_16x16x32_bf16(qf0, f0, acc, 0, 0, 0);
        acc = __builtin_amdgcn_mfma_f32_16x16x32_bf16(qf1, f1, acc, 0, 0, 0);
        __builtin_amdgcn_s_setprio(0);
        const int col = it * 16 + l15;
        #pragma unroll
        for (int reg = 0; reg < 4; ++reg)
            lacc[reg] += (col <= rlim[reg]) ? __builtin_exp2f(acc[reg]) : 0.0f;
    };

    {
        bf16x8 A0, A1, B0, B1;
        ldK(0, A0, A1);
        for (int it = 0; it < total; it += 2) {
            if (it + 1 < total) ldK(it + 1, B0, B1);
            cmpA(it, A0, A1);
            if (it + 2 < total) ldK(it + 2, A0, A1);
            if (it + 1 < total) cmpA(it + 1, B0, B1);
        }
    }

    float pmul[4], pfill[4];
    #pragma unroll
    for (int reg = 0; reg < 4; ++reg) {
        float s = lacc[reg];
        s += __shfl_xor(s, 1);  s += __shfl_xor(s, 2);
        s += __shfl_xor(s, 4);  s += __shfl_xor(s, 8);
        pmul[reg]  = (rlim[reg] < 0) ? 0.0f : 1.0f / s;
        pfill[reg] = (rlim[reg] < 0) ? (1.0f / (float)SL) : 0.0f;
    }

    // ---------------- Phase B: emit P, accumulate O (wave-local, no barriers)
    f32x4 oacc[4];
    #pragma unroll
    for (int nt = 0; nt < 4; ++nt) oacc[nt] = (f32x4){0.0f, 0.0f, 0.0f, 0.0f};

    for (int kc = 0; kc <= lastB; ++kc) {
        const int c0 = kc * KC;
        // QK^T with 1-ahead K pipeline (array[2] indexed by unrolled nt -> static).
        bf16x8 kb0[2], kb1[2];
        ldK(kc * 4, kb0[0], kb1[0]);
        #pragma unroll
        for (int nt = 0; nt < 4; ++nt) {
            if (nt < 3) ldK(kc * 4 + nt + 1, kb0[(nt + 1) & 1], kb1[(nt + 1) & 1]);
            f32x4 acc = {0.0f, 0.0f, 0.0f, 0.0f};
            __builtin_amdgcn_s_setprio(1);
            acc = __builtin_amdgcn_mfma_f32_16x16x32_bf16(qf0, kb0[nt & 1], acc, 0, 0, 0);
            acc = __builtin_amdgcn_mfma_f32_16x16x32_bf16(qf1, kb1[nt & 1], acc, 0, 0, 0);
            __builtin_amdgcn_s_setprio(0);
            const int col = c0 + nt * 16 + l15;
            #pragma unroll
            for (int reg = 0; reg < 4; ++reg) {
                float val = (col <= rlim[reg]) ? __builtin_exp2f(acc[reg]) * pmul[reg]
                                               : pfill[reg];
                slab[(qd * 4 + reg) * LPS + nt * 16 + l15] = val;
            }
        }
        // V loads issued early: latency hides under LDS wait + stores + cvt.
        bf16x8 vb0[2], vb1[2];
        {
            const unsigned short* vr = Vth + (size_t)l15 * SL + c0 + qd * 8;
            vb0[0] = *(const bf16x8*)vr;
            vb1[0] = *(const bf16x8*)(vr + 32);
        }
        // Coalesced P store from wave-local slab (lgkm-ordered by compiler).
        #pragma unroll
        for (int ii = 0; ii < 4; ++ii) {
            int idx = ii * 64 + lane;
            int rr = idx >> 4, c4 = idx & 15;
            *(float4*)(Sout + (size_t)rr * SL + c0 + c4 * 4) =
                *(const float4*)&slab[rr * LPS + c4 * 4];
        }
        // PV A-frags from slab (fp32 -> bf16).
        bf16x8 paf[2];
        #pragma unroll
        for (int kb = 0; kb < 2; ++kb) {
            const float* pr = &slab[l15 * LPS + kb * 32 + qd * 8];
            float4 x = *(const float4*)pr;
            float4 y = *(const float4*)(pr + 4);
            bf16x8 f;
            f[0] = (short)f2bf(x.x); f[1] = (short)f2bf(x.y);
            f[2] = (short)f2bf(x.z); f[3] = (short)f2bf(x.w);
            f[4] = (short)f2bf(y.x); f[5] = (short)f2bf(y.y);
            f[6] = (short)f2bf(y.z); f[7] = (short)f2bf(y.w);
            paf[kb] = f;
        }
        #pragma unroll
        for (int nt = 0; nt < 4; ++nt) {
            if (nt < 3) {
                const unsigned short* vr = Vth + (size_t)((nt + 1) * 16 + l15) * SL + c0 + qd * 8;
                vb0[(nt + 1) & 1] = *(const bf16x8*)vr;
                vb1[(nt + 1) & 1] = *(const bf16x8*)(vr + 32);
            }
            __builtin_amdgcn_s_setprio(1);
            oacc[nt] = __builtin_amdgcn_mfma_f32_16x16x32_bf16(paf[0], vb0[nt & 1], oacc[nt], 0, 0, 0);
            oacc[nt] = __builtin_amdgcn_mfma_f32_16x16x32_bf16(paf[1], vb1[nt & 1], oacc[nt], 0, 0, 0);
            __builtin_amdgcn_s_setprio(0);
        }
    }

    // Zero region (strictly above diagonal; empty when waveDeg).
    {
        float4 z = make_float4(0.0f, 0.0f, 0.0f, 0.0f);
        for (int kc = lastB + 1; kc < NCH; ++kc) {
            const int c0 = kc * KC;
            #pragma unroll
            for (int ii = 0; ii < 4; ++ii) {
                int idx = ii * 64 + lane;
                int rr = idx >> 4, c4 = idx & 15;
                *(float4*)(Sout + (size_t)rr * SL + c0 + c4 * 4) = z;
            }
        }
    }

    // ---------------- O epilogue via wave-local slab -------------------------
    #pragma unroll
    for (int nt = 0; nt < 4; ++nt)
        #pragma unroll
        for (int reg = 0; reg < 4; ++reg)
            slab[(qd * 4 + reg) * LPS + nt * 16 + l15] = oacc[nt][reg];
    #pragma unroll
    for (int ii = 0; ii < 4; ++ii) {
        int idx = ii * 64 + lane;
        int rr = idx >> 4, c4 = idx & 15;
        *(float4*)(Oo + (size_t)rr * DD + c4 * 4) = *(const float4*)&slab[rr * LPS + c4 * 4];
    }
}

extern "C" void kernel_launch(void* const* d_in, const int* in_sizes, int n_in,
                              void* d_out, int out_size, void* d_ws, size_t ws_size,
                              hipStream_t stream)
{
    const float* q  = (const float*)d_in[0];
    const float* k  = (const float*)d_in[1];
    const float* v  = (const float*)d_in[2];
    const float* mk = (const float*)d_in[3];
    const int*   mn = (const int*)d_in[4];
    float* out = (float*)d_out;

    const size_t nElem = (size_t)NB * NH * SL * DD;   // 4,194,304
    unsigned short* Qb = (unsigned short*)d_ws;
    unsigned short* Kp = Qb + nElem;
    unsigned short* Vp = Kp + nElem;

    const int n4 = (int)(nElem / 4);
    // Q pre-scaled by (1/8)*log2(e): QK^T lands directly in exp2 domain.
    cvt_bf16<<<n4 / 256, 256, 0, stream>>>(q, Qb, n4, 0.125f * 1.44269504f);
    cvt_bf16<<<n4 / 256, 256, 0, stream>>>(k, Kp, n4, 1.0f);
    transpose_v<<<NB * NH * (SL / 64), 256, 0, stream>>>(v, Vp);

    // 1024 blocks: 32 fold-pairs x 32 bh, XCD-interleaved.
    attn_mfma<<<1024, NT, 0, stream>>>(Qb, Kp, Vp, mk, mn, out);
}

// Round 5
// 744.498 us; speedup vs baseline: 1.0304x; 1.0304x over previous
//
#include <hip/hip_runtime.h>
#include <math.h>

// B=2,H=16,S=2048,D=64 fp32 attention, outputs (O, P). MFMA bf16.
// 2048 blocks x 4 waves; each block = fold-pair (16-row group g and 127-g),
// each group's K-range split across 2 waves -> 32 waves/CU residency.
#define NB 2
#define NH 16
#define SL 2048
#define DD 64
#define KC 64
#define NCH (SL / KC)
#define NT 256
#define LPS 68           // slab fp32 row stride (pad +4)

typedef short bf16x8 __attribute__((ext_vector_type(8)));
typedef float f32x4  __attribute__((ext_vector_type(4)));

__device__ __forceinline__ unsigned short f2bf(float x) {
    unsigned u = __float_as_uint(x);
    u += 0x7fffu + ((u >> 16) & 1u);     // round-to-nearest-even
    return (unsigned short)(u >> 16);
}

// LDS-only barrier: waits local ops, leaves global loads/stores in flight.
__device__ __forceinline__ void lds_barrier() {
    asm volatile("s_waitcnt lgkmcnt(0)\n\ts_barrier" ::: "memory");
}

// ---------------- prep: fp32 -> bf16 elementwise (Q scaled, K raw) -----------
__global__ __launch_bounds__(256)
void cvt_bf16(const float* __restrict__ in, unsigned short* __restrict__ out,
              int n4, float scale)
{
    int i = blockIdx.x * 256 + threadIdx.x;
    if (i >= n4) return;
    float4 v = ((const float4*)in)[i];
    ushort4 o;
    o.x = f2bf(v.x * scale); o.y = f2bf(v.y * scale);
    o.z = f2bf(v.z * scale); o.w = f2bf(v.w * scale);
    ((ushort4*)out)[i] = o;
}

// ---------------- prep: V[bh][s][d] fp32 -> Vt[bh][d][s] bf16 ----------------
__global__ __launch_bounds__(256)
void transpose_v(const float* __restrict__ V, unsigned short* __restrict__ Vt)
{
    __shared__ __align__(16) unsigned short vt[64 * 72];  // [d][r], stride 72
    const int bh = blockIdx.x >> 5;
    const int s0 = (blockIdx.x & 31) * 64;
    const int t  = threadIdx.x;

    const float4* src = (const float4*)(V + ((size_t)bh * SL + s0) * DD);
    #pragma unroll
    for (int i = 0; i < 4; ++i) {
        int idx = t + i * 256;
        int r = idx >> 4, d4 = idx & 15;
        float4 v = src[r * 16 + d4];
        vt[(d4 * 4 + 0) * 72 + r] = f2bf(v.x);
        vt[(d4 * 4 + 1) * 72 + r] = f2bf(v.y);
        vt[(d4 * 4 + 2) * 72 + r] = f2bf(v.z);
        vt[(d4 * 4 + 3) * 72 + r] = f2bf(v.w);
    }
    __syncthreads();
    const int d = t >> 2, seg = t & 3;
    unsigned short* dst = Vt + ((size_t)bh * DD + d) * SL + s0 + seg * 16;
    uint4 p0 = *(const uint4*)&vt[d * 72 + seg * 16];
    uint4 p1 = *(const uint4*)&vt[d * 72 + seg * 16 + 8];
    *(uint4*)dst = p0;
    *(uint4*)(dst + 8) = p1;
}

// ---------------- main fused attention ---------------------------------------
__global__ __launch_bounds__(NT, 4)
void attn_mfma(const unsigned short* __restrict__ Qb,
               const unsigned short* __restrict__ Kb,
               const unsigned short* __restrict__ Vt,
               const float* __restrict__ Mg,
               const int* __restrict__ MNg,
               float* __restrict__ Og)
{
    // Per-ROLE slab (wave-private during Phase B; shared only at combines).
    __shared__ __align__(16) float ps[4][16 * LPS];
    __shared__ float lsx[4][16];

    const int tid  = threadIdx.x;
    const int w    = tid >> 6;
    const int lane = tid & 63;
    const int l15  = lane & 15;
    const int qd   = lane >> 4;

    // 2048 blocks: xcd = lin&7 (HW RR), 256 per XCD covering 4 bh x 64 pairs.
    const int lin  = blockIdx.x;
    const int xcd  = lin & 7;
    const int iloc = lin >> 3;          // 0..255
    const int bh   = xcd * 4 + (iloc >> 6);
    const int g    = iloc & 63;         // fold-pair id (groups g and 127-g)
    const int j    = (iloc >> 5) & 7;   // varies across blocks on same CU slot
    const int b    = bh >> 4;

    // role 0,1: low group k-halves; role 2,3: high group k-halves.
    const int role  = (w + j) & 3;
    const int khalf = role & 1;
    const int r0    = (role < 2) ? g * 16 : 2032 - g * 16;

    const int diag = (MNg[0] != 0) ? -1 : 0;

    // Rows owned by this lane: r0 + qd*4 + reg.  rlim<0 <=> degenerate row.
    int rlim[4]; int anyDeg = 0;
    #pragma unroll
    for (int reg = 0; reg < 4; ++reg) {
        int row = r0 + qd * 4 + reg;
        float m = Mg[(size_t)b * SL + row];
        int rl = row + diag;
        if (m == 0.0f) rl = -1;
        rlim[reg] = rl;
        anyDeg |= (rl < 0);
    }
    const bool grpDeg = __any(anyDeg);          // same for both partner waves
    const int lastB = grpDeg ? (NCH - 1) : ((r0 + 15 + diag) >> 6);
    const int N     = lastB + 1;                // compute chunks for this group
    const int kcMid = N >> 1;
    const int kcBeg = khalf ? kcMid : 0;
    const int kcEnd = khalf ? N : kcMid;

    const unsigned short* Qh  = Qb + (size_t)bh * SL * DD;
    const unsigned short* Kh  = Kb + (size_t)bh * SL * DD;
    const unsigned short* Vth = Vt + (size_t)bh * DD * SL;
    float* Oo   = Og + ((size_t)bh * SL + r0) * DD;
    float* Sout = Og + (size_t)NB * NH * SL * DD
                     + (size_t)bh * SL * SL + (size_t)r0 * SL;
    float* slab = ps[role];

    // Q A-frags (persistent). Q pre-scaled by 0.125*log2(e): P = exp2(acc).
    const unsigned short* qrow = Qh + (size_t)(r0 + l15) * DD + qd * 8;
    bf16x8 qf0 = *(const bf16x8*)qrow;
    bf16x8 qf1 = *(const bf16x8*)(qrow + 32);

    auto ldK = [&](int it, bf16x8& f0, bf16x8& f1) {
        const unsigned short* kr = Kh + (size_t)(it * 16 + l15) * DD + qd * 8;
        f0 = *(const bf16x8*)kr;
        f1 = *(const bf16x8*)(kr + 32);
    };

    // ---------------- Phase A: partial row sums over [kcBeg, kcEnd) ----------
    float lacc[4] = {0.0f, 0.0f, 0.0f, 0.0f};
    {
        const int t0 = kcBeg * 4;
        const int T  = (kcEnd - kcBeg) * 4;     // 16-col tiles
        auto cmpA = [&](int it, bf16x8 f0, bf16x8 f1) {
            f32x4 acc = {0.0f, 0.0f, 0.0f, 0.0f};
            __builtin_amdgcn_s_setprio(1);
            acc = __builtin_amdgcn_mfma_f32_16x16x32_bf16(qf0, f0, acc, 0, 0, 0);
            acc = __builtin_amdgcn_mfma_f32_16x16x32_bf16(qf1, f1, acc, 0, 0, 0);
            __builtin_amdgcn_s_setprio(0);
            const int col = it * 16 + l15;
            #pragma unroll
            for (int reg = 0; reg < 4; ++reg)
                lacc[reg] += (col <= rlim[reg]) ? __builtin_exp2f(acc[reg]) : 0.0f;
        };
        if (T > 0) {
            bf16x8 A0, A1, B0, B1;
            ldK(t0, A0, A1);
            for (int t = 0; t < T; t += 2) {
                if (t + 1 < T) ldK(t0 + t + 1, B0, B1);
                cmpA(t0 + t, A0, A1);
                if (t + 2 < T) ldK(t0 + t + 2, A0, A1);
                if (t + 1 < T) cmpA(t0 + t + 1, B0, B1);
            }
        }
    }

    // Intra-wave reduce over l15, then cross-wave combine with k-half partner.
    float lsum[4];
    #pragma unroll
    for (int reg = 0; reg < 4; ++reg) {
        float s = lacc[reg];
        s += __shfl_xor(s, 1);  s += __shfl_xor(s, 2);
        s += __shfl_xor(s, 4);  s += __shfl_xor(s, 8);
        lsum[reg] = s;
    }
    if (l15 == 0) {
        #pragma unroll
        for (int reg = 0; reg < 4; ++reg)
            lsx[role][qd * 4 + reg] = lsum[reg];
    }
    lds_barrier();
    float pmul[4], pfill[4];
    #pragma unroll
    for (int reg = 0; reg < 4; ++reg) {
        float tot = lsum[reg] + lsx[role ^ 1][qd * 4 + reg];
        pmul[reg]  = (rlim[reg] < 0) ? 0.0f : 1.0f / tot;
        pfill[reg] = (rlim[reg] < 0) ? (1.0f / (float)SL) : 0.0f;
    }

    // ---------------- Phase B: emit P, accumulate partial O ------------------
    f32x4 oacc[4];
    #pragma unroll
    for (int nt = 0; nt < 4; ++nt) oacc[nt] = (f32x4){0.0f, 0.0f, 0.0f, 0.0f};

    for (int kc = kcBeg; kc < kcEnd; ++kc) {
        const int c0 = kc * KC;
        bf16x8 kb0[2], kb1[2];
        ldK(kc * 4, kb0[0], kb1[0]);
        #pragma unroll
        for (int nt = 0; nt < 4; ++nt) {
            if (nt < 3) ldK(kc * 4 + nt + 1, kb0[(nt + 1) & 1], kb1[(nt + 1) & 1]);
            f32x4 acc = {0.0f, 0.0f, 0.0f, 0.0f};
            __builtin_amdgcn_s_setprio(1);
            acc = __builtin_amdgcn_mfma_f32_16x16x32_bf16(qf0, kb0[nt & 1], acc, 0, 0, 0);
            acc = __builtin_amdgcn_mfma_f32_16x16x32_bf16(qf1, kb1[nt & 1], acc, 0, 0, 0);
            __builtin_amdgcn_s_setprio(0);
            const int col = c0 + nt * 16 + l15;
            #pragma unroll
            for (int reg = 0; reg < 4; ++reg) {
                float val = (col <= rlim[reg]) ? __builtin_exp2f(acc[reg]) * pmul[reg]
                                               : pfill[reg];
                slab[(qd * 4 + reg) * LPS + nt * 16 + l15] = val;
            }
        }
        // V loads issued early; consumed after stores+cvt.
        bf16x8 vb0[2], vb1[2];
        {
            const unsigned short* vr = Vth + (size_t)l15 * SL + c0 + qd * 8;
            vb0[0] = *(const bf16x8*)vr;
            vb1[0] = *(const bf16x8*)(vr + 32);
        }
        // Coalesced P store from wave-local slab (same-wave lgkm ordering).
        #pragma unroll
        for (int ii = 0; ii < 4; ++ii) {
            int idx = ii * 64 + lane;
            int rr = idx >> 4, c4 = idx & 15;
            *(float4*)(Sout + (size_t)rr * SL + c0 + c4 * 4) =
                *(const float4*)&slab[rr * LPS + c4 * 4];
        }
        // PV A-frags from slab (fp32 -> bf16).
        bf16x8 paf[2];
        #pragma unroll
        for (int kb = 0; kb < 2; ++kb) {
            const float* pr = &slab[l15 * LPS + kb * 32 + qd * 8];
            float4 x = *(const float4*)pr;
            float4 y = *(const float4*)(pr + 4);
            bf16x8 f;
            f[0] = (short)f2bf(x.x); f[1] = (short)f2bf(x.y);
            f[2] = (short)f2bf(x.z); f[3] = (short)f2bf(x.w);
            f[4] = (short)f2bf(y.x); f[5] = (short)f2bf(y.y);
            f[6] = (short)f2bf(y.z); f[7] = (short)f2bf(y.w);
            paf[kb] = f;
        }
        #pragma unroll
        for (int nt = 0; nt < 4; ++nt) {
            if (nt < 3) {
                const unsigned short* vr = Vth + (size_t)((nt + 1) * 16 + l15) * SL + c0 + qd * 8;
                vb0[(nt + 1) & 1] = *(const bf16x8*)vr;
                vb1[(nt + 1) & 1] = *(const bf16x8*)(vr + 32);
            }
            __builtin_amdgcn_s_setprio(1);
            oacc[nt] = __builtin_amdgcn_mfma_f32_16x16x32_bf16(paf[0], vb0[nt & 1], oacc[nt], 0, 0, 0);
            oacc[nt] = __builtin_amdgcn_mfma_f32_16x16x32_bf16(paf[1], vb1[nt & 1], oacc[nt], 0, 0, 0);
            __builtin_amdgcn_s_setprio(0);
        }
    }

    // Zero region of this group: chunks [N..32), split between the two waves.
    {
        const int zMid = N + ((NCH - N) >> 1);
        const int zb = khalf ? zMid : N;
        const int ze = khalf ? NCH : zMid;
        float4 z = make_float4(0.0f, 0.0f, 0.0f, 0.0f);
        for (int kc = zb; kc < ze; ++kc) {
            const int c0 = kc * KC;
            #pragma unroll
            for (int ii = 0; ii < 4; ++ii) {
                int idx = ii * 64 + lane;
                int rr = idx >> 4, c4 = idx & 15;
                *(float4*)(Sout + (size_t)rr * SL + c0 + c4 * 4) = z;
            }
        }
    }

    // ---------------- O: combine partner halves via LDS, coalesced store -----
    #pragma unroll
    for (int nt = 0; nt < 4; ++nt)
        #pragma unroll
        for (int reg = 0; reg < 4; ++reg)
            slab[(qd * 4 + reg) * LPS + nt * 16 + l15] = oacc[nt][reg];
    lds_barrier();
    {
        const float* sA = ps[role & ~1];
        const float* sB = ps[role | 1];
        #pragma unroll
        for (int ii = 0; ii < 2; ++ii) {
            int idx = ii * 64 + lane;
            int rr = (idx >> 4) + khalf * 8;    // this wave stores 8 rows
            int c4 = idx & 15;
            float4 a = *(const float4*)&sA[rr * LPS + c4 * 4];
            float4 bv = *(const float4*)&sB[rr * LPS + c4 * 4];
            float4 o = make_float4(a.x + bv.x, a.y + bv.y, a.z + bv.z, a.w + bv.w);
            *(float4*)(Oo + (size_t)rr * DD + c4 * 4) = o;
        }
    }
}

extern "C" void kernel_launch(void* const* d_in, const int* in_sizes, int n_in,
                              void* d_out, int out_size, void* d_ws, size_t ws_size,
                              hipStream_t stream)
{
    const float* q  = (const float*)d_in[0];
    const float* k  = (const float*)d_in[1];
    const float* v  = (const float*)d_in[2];
    const float* mk = (const float*)d_in[3];
    const int*   mn = (const int*)d_in[4];
    float* out = (float*)d_out;

    const size_t nElem = (size_t)NB * NH * SL * DD;   // 4,194,304
    unsigned short* Qb = (unsigned short*)d_ws;
    unsigned short* Kp = Qb + nElem;
    unsigned short* Vp = Kp + nElem;

    const int n4 = (int)(nElem / 4);
    // Q pre-scaled by (1/8)*log2(e): QK^T lands directly in exp2 domain.
    cvt_bf16<<<n4 / 256, 256, 0, stream>>>(q, Qb, n4, 0.125f * 1.44269504f);
    cvt_bf16<<<n4 / 256, 256, 0, stream>>>(k, Kp, n4, 1.0f);
    transpose_v<<<NB * NH * (SL / 64), 256, 0, stream>>>(v, Vp);

    // 2048 blocks: 8 XCD x (4 bh x 64 fold-pairs) -> 8 blocks/CU, 32 waves/CU.
    attn_mfma<<<2048, NT, 0, stream>>>(Qb, Kp, Vp, mk, mn, out);
}